// Round 12
// baseline (348.646 us; speedup 1.0000x reference)
//
#include <hip/hip_runtime.h>
#include <stdint.h>

#define D_MODEL 1024
#define KDIM 1024             // all three GEMMs have K=1024 (compile-time)
#define BATCH 4
#define SEQ 4096
#define MROWS (BATCH*SEQ)     // 16384
#define CHUNK 64
#define NCHUNK (SEQ/CHUNK)    // 64

typedef unsigned short u16;
typedef __attribute__((ext_vector_type(8))) short short8;
typedef __attribute__((ext_vector_type(4))) float f32x4;
typedef __attribute__((ext_vector_type(16))) float f32x16;
typedef __attribute__((ext_vector_type(4))) unsigned short u16x4;

__device__ __forceinline__ u16 f2bf(float f){
  uint32_t b = __builtin_bit_cast(uint32_t, f);
  b += 0x7FFFu + ((b >> 16) & 1u);
  return (u16)(b >> 16);
}
__device__ __forceinline__ float bf2f(u16 u){
  uint32_t b = ((uint32_t)u) << 16;
  return __builtin_bit_cast(float, b);
}

// ---------------- fused prep (weights fp32->bf16 + bias concat) + layernorm ----------
__global__ __launch_bounds__(256) void prep_ln_kernel(
    const float* __restrict__ w_in, const float* __restrict__ w_delta,
    const float* __restrict__ w_B, const float* __restrict__ w_C,
    const float* __restrict__ w_out,
    const float* __restrict__ b_delta, const float* __restrict__ b_B,
    const float* __restrict__ b_C,
    u16* __restrict__ w_in_bf, u16* __restrict__ wcat_bf,
    u16* __restrict__ w_out_bf, float* __restrict__ bcat,
    const float* __restrict__ x, const float* __restrict__ g,
    const float* __restrict__ bb, u16* __restrict__ h){
  if (blockIdx.x >= 6147){
    // ---- LN ----
    int row = blockIdx.x - 6147;
    int tid = threadIdx.x, lane = tid & 63, wid = tid >> 6;
    const float* xr = x + (size_t)row * D_MODEL;
    float4 v = *(const float4*)(xr + tid * 4);
    float s  = v.x + v.y + v.z + v.w;
    float s2 = v.x*v.x + v.y*v.y + v.z*v.z + v.w*v.w;
#pragma unroll
    for (int off = 32; off > 0; off >>= 1){ s += __shfl_down(s, off); s2 += __shfl_down(s2, off); }
    __shared__ float red[8];
    if (lane == 0){ red[wid] = s; red[4 + wid] = s2; }
    __syncthreads();
    s  = red[0] + red[1] + red[2] + red[3];
    s2 = red[4] + red[5] + red[6] + red[7];
    float mu  = s * (1.f / D_MODEL);
    float var = s2 * (1.f / D_MODEL) - mu * mu;
    float rs  = rsqrtf(var + 1e-5f);
    int c = tid * 4;
    u16x4 o;
    o.x = f2bf((v.x - mu) * rs * g[c+0] + bb[c+0]);
    o.y = f2bf((v.y - mu) * rs * g[c+1] + bb[c+1]);
    o.z = f2bf((v.z - mu) * rs * g[c+2] + bb[c+2]);
    o.w = f2bf((v.w - mu) * rs * g[c+3] + bb[c+3]);
    *(u16x4*)(h + (size_t)row * D_MODEL + c) = o;
    return;
  }
  // ---- weight prep ----
  int i4 = blockIdx.x * 256 + threadIdx.x;   // 4-element units
  const float* src; u16* dst; int off;
  if      (i4 <  524288){ src = w_in;    dst = w_in_bf;           off = i4; }
  else if (i4 <  786432){ src = w_delta; dst = wcat_bf;           off = i4 -  524288; }
  else if (i4 < 1048576){ src = w_B;     dst = wcat_bf + 1048576; off = i4 -  786432; }
  else if (i4 < 1310720){ src = w_C;     dst = wcat_bf + 2097152; off = i4 - 1048576; }
  else if (i4 < 1572864){ src = w_out;   dst = w_out_bf;          off = i4 - 1310720; }
  else {
    int t = i4 - 1572864;    // 768 threads copy 3072 bias floats
    if      (t < 256){ *(float4*)(bcat +        t*4)        = *(const float4*)(b_delta + t*4); }
    else if (t < 512){ *(float4*)(bcat + 1024 + (t-256)*4)  = *(const float4*)(b_B + (t-256)*4); }
    else if (t < 768){ *(float4*)(bcat + 2048 + (t-512)*4)  = *(const float4*)(b_C + (t-512)*4); }
    return;
  }
  float4 v = *(const float4*)(src + (size_t)off * 4);
  u16x4 o; o.x = f2bf(v.x); o.y = f2bf(v.y); o.z = f2bf(v.z); o.w = f2bf(v.w);
  *(u16x4*)(dst + (size_t)off * 4) = o;
}

// ---------------- 256x256 bf16 MFMA GEMM, BK=32, ring-4, 32x32x16 MFMA --------------
// R6 schedule byte-identical (one barrier/K-tile, stage k+3, vmcnt(8), drain 8/4/0,
// swizzle byte ^= ((row>>1)&3)<<4 — R5-verified 0 conflicts; read pattern audit:
// lanes 0-15 hit rows 0-15 slot (lhi*16)^key, identical bank walk to R5's).
// CHANGE: v_mfma_f32_32x32x16_bf16 (m119: 2495 TF vs 2176 for 16x16 family).
// Wave = 128x64 = 4x2 frags of 32x32, 16 MFMA/tile (was 32), same 12 ds_read_b128,
// same 128 AGPR.  A/B operand: row=lane&31, k=(lane>>5)*8 (+h*16 via slot^32).
// C/D (m74/m101-verified): col=lane&31, row=(reg&3)+8*(reg>>2)+4*(lane>>5).
// EPI 0: store bf16(out).  EPI 1: store fp32(out + resid).
#define VMCNT_(N) asm volatile("s_waitcnt vmcnt(" #N ")" ::: "memory")
#define VMCNT(N) VMCNT_(N)

template<int EPI>
__global__ __launch_bounds__(512, 2) void gemm256(
    const u16* __restrict__ A, const u16* __restrict__ W,
    const float* __restrict__ bias,
    u16* __restrict__ outb, float* __restrict__ outf,
    const float* __restrict__ resid, int N){
  __shared__ char lds[131072];   // A bufs: [0,64KB) ; B bufs: [64KB,128KB)
  const int tid = threadIdx.x, wid = tid >> 6, lane = tid & 63;
  const int wm = wid >> 2, wn = wid & 3;
  const int l31 = lane & 31, lhi = lane >> 5;

  int nwg = gridDim.x;
  int cpx = nwg >> 3;
  int bid = blockIdx.x;
  int wg = (bid & 7) * cpx + (bid >> 3);
  int ntile = N >> 8;
  int by = wg / ntile, bx = wg % ntile;
  int m0 = by << 8, n0 = bx << 8;

  f32x16 acc[4][2];
#pragma unroll
  for (int i = 0; i < 4; i++)
#pragma unroll
    for (int j = 0; j < 2; j++)
#pragma unroll
      for (int e = 0; e < 16; e++) acc[i][j][e] = 0.f;

  // hoisted swizzled LDS read offsets (row stride 64B, xor ((row>>1)&3)<<4)
  const int key = ((l31 >> 1) & 3) << 4;
  const int slot0 = (lhi * 16) ^ key;
  const int aOff = (wm * 128 + l31) * 64 + slot0;
  const int bOff = (wn * 64  + l31) * 64 + slot0;

  // hoisted staging addresses (inverse-swizzled global source, linear LDS dest)
  const int rS = tid >> 2;
  const int cbS = ((tid & 3) * 16) ^ (((rS >> 1) & 3) << 4);
  const u16* gA = A + (size_t)(m0 + rS) * KDIM + (cbS >> 1);
  const u16* gB = W + (size_t)(n0 + rS) * KDIM + (cbS >> 1);

  auto stA = [&](int kt, int bi){
    const u16* g0 = gA + kt;
    unsigned l0 = (unsigned)(bi * 16384 + wid * 1024);
    __builtin_amdgcn_global_load_lds((const __attribute__((address_space(1))) void*)g0,
                                     (__attribute__((address_space(3))) void*)(lds + l0), 16, 0, 0);
    __builtin_amdgcn_global_load_lds((const __attribute__((address_space(1))) void*)(g0 + 128 * KDIM),
                                     (__attribute__((address_space(3))) void*)(lds + l0 + 8192), 16, 0, 0);
  };
  auto stB = [&](int kt, int bi){
    const u16* g0 = gB + kt;
    unsigned l0 = (unsigned)(65536 + bi * 16384 + wid * 1024);
    __builtin_amdgcn_global_load_lds((const __attribute__((address_space(1))) void*)g0,
                                     (__attribute__((address_space(3))) void*)(lds + l0), 16, 0, 0);
    __builtin_amdgcn_global_load_lds((const __attribute__((address_space(1))) void*)(g0 + 128 * KDIM),
                                     (__attribute__((address_space(3))) void*)(lds + l0 + 8192), 16, 0, 0);
  };

#define TILE(BI, STKT, DOSTAGE, WAITC) { \
  const char* pa = lds + (BI) * 16384; \
  const char* pb = lds + 65536 + (BI) * 16384; \
  short8 bfr[2][2], afr[4][2]; \
  _Pragma("unroll") \
  for (int ni = 0; ni < 2; ni++){ \
    bfr[ni][0] = *(const short8*)(pb + (bOff + ni * 2048)); \
    bfr[ni][1] = *(const short8*)(pb + ((bOff + ni * 2048) ^ 32)); \
  } \
  _Pragma("unroll") \
  for (int mi = 0; mi < 4; mi++){ \
    afr[mi][0] = *(const short8*)(pa + (aOff + mi * 2048)); \
    afr[mi][1] = *(const short8*)(pa + ((aOff + mi * 2048) ^ 32)); \
  } \
  if (DOSTAGE){ stA((STKT), ((BI) + 3) & 3); stB((STKT), ((BI) + 3) & 3); } \
  __builtin_amdgcn_sched_barrier(0); \
  __builtin_amdgcn_s_setprio(1); \
  _Pragma("unroll") \
  for (int h = 0; h < 2; h++) \
    _Pragma("unroll") \
    for (int mi = 0; mi < 4; mi++) \
      _Pragma("unroll") \
      for (int ni = 0; ni < 2; ni++) \
        acc[mi][ni] = __builtin_amdgcn_mfma_f32_32x32x16_bf16(afr[mi][h], bfr[ni][h], acc[mi][ni], 0, 0, 0); \
  __builtin_amdgcn_s_setprio(0); \
  WAITC; \
  __builtin_amdgcn_s_barrier(); \
}

  // prologue: stage tiles 0,1,2; wait tile 0 landed (8 still outstanding)
  stA(0, 0);  stB(0, 0);
  stA(32, 1); stB(32, 1);
  stA(64, 2); stB(64, 2);
  VMCNT(8);
  __builtin_amdgcn_s_barrier();

  // tiles 0..27: steady state (tile k stages tile k+3, end-wait vmcnt(8))
  for (int kk = 0; kk < 28; kk += 4){
    TILE(0, (kk + 3) << 5, 1, VMCNT(8));
    TILE(1, (kk + 4) << 5, 1, VMCNT(8));
    TILE(2, (kk + 5) << 5, 1, VMCNT(8));
    TILE(3, (kk + 6) << 5, 1, VMCNT(8));
  }
  // tile 28 stages tile 31; then drain
  TILE(0, 992, 1, VMCNT(8));
  TILE(1, 0, 0, VMCNT(4));
  TILE(2, 0, 0, VMCNT(0));
  TILE(3, 0, 0, (void)0);
#undef TILE

  // epilogue: 32x32 C/D layout: col=lane&31, row=(reg&3)+8*(reg>>2)+4*lhi
  float bv[2];
#pragma unroll
  for (int ni = 0; ni < 2; ni++) bv[ni] = bias[n0 + wn * 64 + ni * 32 + l31];
#pragma unroll
  for (int mi = 0; mi < 4; mi++){
#pragma unroll
    for (int ni = 0; ni < 2; ni++){
      int c = n0 + wn * 64 + ni * 32 + l31;
#pragma unroll
      for (int reg = 0; reg < 16; reg++){
        int row = (reg & 3) + 8 * (reg >> 2) + 4 * lhi;
        int r = m0 + wm * 128 + mi * 32 + row;
        float val = acc[mi][ni][reg] + bv[ni];
        size_t o = (size_t)r * N + c;
        if (EPI == 0) outb[o] = f2bf(val);
        else          outf[o] = val + resid[o];
      }
    }
  }
}

// ---------------- depthwise causal conv1d (K=4), sliding-window ----------------
__global__ __launch_bounds__(256) void conv_kernel(const u16* __restrict__ uv,
    const float* __restrict__ wc, const float* __restrict__ bc, u16* __restrict__ uc){
  int idx = blockIdx.x * 256 + threadIdx.x;   // (MROWS/16) segs x 128 d-groups
  int d0 = (idx & 127) * 8;
  int m0 = (idx >> 7) * 16;
  int l0 = m0 & (SEQ - 1);
  float4 wv[8]; float bias[8];
#pragma unroll
  for (int j = 0; j < 8; j++){ wv[j] = *(const float4*)(wc + (d0 + j) * 4); bias[j] = bc[d0 + j]; }
  short8 zero8 = {0,0,0,0,0,0,0,0};
  short8 w0 = zero8, w1 = zero8, w2 = zero8;
  if (l0 > 0){
    w0 = *(const short8*)(uv + (size_t)(m0 - 3) * 2048 + d0);
    w1 = *(const short8*)(uv + (size_t)(m0 - 2) * 2048 + d0);
    w2 = *(const short8*)(uv + (size_t)(m0 - 1) * 2048 + d0);
  }
  const u16* pi = uv + (size_t)m0 * 2048 + d0;
  u16* po = uc + (size_t)m0 * 1024 + d0;
#pragma unroll 4
  for (int t = 0; t < 16; t++){
    short8 cur = *(const short8*)pi;  pi += 2048;
    short8 o;
#pragma unroll
    for (int j = 0; j < 8; j++){
      float a = bias[j] + bf2f((u16)w0[j]) * wv[j].x + bf2f((u16)w1[j]) * wv[j].y
                        + bf2f((u16)w2[j]) * wv[j].z + bf2f((u16)cur[j]) * wv[j].w;
      o[j] = (short)f2bf(a);
    }
    *(short8*)po = o;  po += 1024;
    w0 = w1; w1 = w2; w2 = cur;
  }
}

// ---------------- scan pass A: local scan + G=cumdec*C + y_local + P,S -------------
__global__ __launch_bounds__(256) void scanA(const u16* __restrict__ dbc, const u16* __restrict__ uc,
                                             u16* __restrict__ G, float* __restrict__ P,
                                             float* __restrict__ S, float* __restrict__ ylocal){
  int b = blockIdx.x >> 6, c = blockIdx.x & (NCHUNK - 1);
  int tid = threadIdx.x, n0 = tid * 4;
  __shared__ float part[CHUNK][257];
  __shared__ float red2[CHUNK][5];
  size_t mbase = (size_t)b * SEQ + c * CHUNK;
  float Pv[4] = {1.f,1.f,1.f,1.f}, Sv[4] = {0.f,0.f,0.f,0.f};
  const u16* pd = dbc + mbase * 3072 + n0;
  const u16* pu = uc + mbase * 1024 + n0;
  u16* pg = G + mbase * 1024 + n0;
#pragma unroll 2
  for (int t = 0; t < CHUNK; t++){
    u16x4 dr = *(const u16x4*)pd;
    u16x4 bm = *(const u16x4*)(pd + 1024);
    u16x4 cm = *(const u16x4*)(pd + 2048);
    u16x4 uu = *(const u16x4*)pu;
    pd += 3072; pu += 1024;
    float contrib = 0.f;
    u16x4 go;
#pragma unroll
    for (int j = 0; j < 4; j++){
      float dec = 1.f / (1.f + __expf(bf2f(dr[j])));   // exp(-softplus) == sigmoid(-x)
      float cf = bf2f(cm[j]);
      Pv[j] *= dec;
      Sv[j] = Sv[j] * dec + bf2f(uu[j]) * bf2f(bm[j]);
      go[j] = f2bf(Pv[j] * cf);
      contrib += Sv[j] * cf;
    }
    *(u16x4*)pg = go;  pg += 1024;
    part[t][tid] = contrib;
  }
  __syncthreads();
  {
    int t = tid & 63, q = tid >> 6;
    float s = 0.f;
#pragma unroll
    for (int j = 0; j < 64; j++) s += part[t][q * 64 + j];
    red2[t][q] = s;
  }
  __syncthreads();
  if (tid < CHUNK)
    ylocal[mbase + tid] = red2[tid][0] + red2[tid][1] + red2[tid][2] + red2[tid][3];
  int o = (b * NCHUNK + c) * 1024 + n0;
  float4 p4 = {Pv[0], Pv[1], Pv[2], Pv[3]};
  float4 s4 = {Sv[0], Sv[1], Sv[2], Sv[3]};
  *(float4*)(P + o) = p4;
  *(float4*)(S + o) = s4;
}

// ---------------- pass B: chunk-level scan (float4) ----------------
__global__ void scanB(const float* __restrict__ P, const float* __restrict__ S,
                      float* __restrict__ Hin){
  int idx = blockIdx.x * 256 + threadIdx.x;  // 1024 threads
  int n0 = (idx & 255) * 4, b = idx >> 8;
  float4 H = {0.f,0.f,0.f,0.f};
  for (int c = 0; c < NCHUNK; c++){
    int o = (b * NCHUNK + c) * 1024 + n0;
    *(float4*)(Hin + o) = H;
    float4 p = *(const float4*)(P + o);
    float4 s = *(const float4*)(S + o);
    H.x = H.x * p.x + s.x;  H.y = H.y * p.y + s.y;
    H.z = H.z * p.z + s.z;  H.w = H.w * p.w + s.w;
  }
}

// ---------------- pass C': y = y_local + Hin.G  + fused gate ----------------------
__global__ __launch_bounds__(256) void scanC(u16* gbuf, const float* __restrict__ Hin,
                                             const float* __restrict__ ylocal,
                                             const u16* __restrict__ uv){
  int b = blockIdx.x >> 6, c = blockIdx.x & (NCHUNK - 1);
  int tid = threadIdx.x, n0 = tid * 4;
  __shared__ float part[CHUNK][257];
  __shared__ float red2[CHUNK][5];
  __shared__ float ys[CHUNK];
  size_t mbase = (size_t)b * SEQ + c * CHUNK;
  float4 h4 = *(const float4*)(Hin + (b * NCHUNK + c) * 1024 + n0);
  const u16* pG = gbuf + mbase * 1024 + n0;
#pragma unroll 4
  for (int t = 0; t < CHUNK; t++){
    u16x4 g = *(const u16x4*)pG;  pG += 1024;
    part[t][tid] = h4.x * bf2f(g.x) + h4.y * bf2f(g.y)
                 + h4.z * bf2f(g.z) + h4.w * bf2f(g.w);
  }
  __syncthreads();
  {
    int t = tid & 63, q = tid >> 6;
    float s = 0.f;
#pragma unroll
    for (int j = 0; j < 64; j++) s += part[t][q * 64 + j];
    red2[t][q] = s;
  }
  __syncthreads();
  if (tid < CHUNK)
    ys[tid] = red2[tid][0] + red2[tid][1] + red2[tid][2] + red2[tid][3] + ylocal[mbase + tid];
  __syncthreads();
  // fused gate: gg[mbase+t][d] = bf16( y[t] * sigmoid(v[mbase+t][d]) ), overwrites G rows
  const u16* pv = uv + mbase * 2048 + 1024;
  u16* pg = gbuf + mbase * 1024;
#pragma unroll 4
  for (int i2 = 0; i2 < 32; i2++){
    int e = i2 * 256 + tid;
    int t = e >> 7, ch = e & 127;
    short8 v = *(const short8*)(pv + (size_t)t * 2048 + ch * 8);
    float yv = ys[t];
    short8 o;
#pragma unroll
    for (int j = 0; j < 8; j++){
      float vf = bf2f((u16)v[j]);
      float sg = 1.f / (1.f + __expf(-vf));
      o[j] = (short)f2bf(yv * sg);
    }
    *(short8*)(pg + (size_t)t * 1024 + ch * 8) = o;
  }
}

extern "C" void kernel_launch(void* const* d_in, const int* in_sizes, int n_in,
                              void* d_out, int out_size, void* d_ws, size_t ws_size,
                              hipStream_t stream) {
  const float* x      = (const float*)d_in[0];
  const float* ln_g   = (const float*)d_in[1];
  const float* ln_b   = (const float*)d_in[2];
  const float* w_in   = (const float*)d_in[3];
  const float* b_in   = (const float*)d_in[4];
  const float* w_conv = (const float*)d_in[5];
  const float* b_conv = (const float*)d_in[6];
  const float* w_delta= (const float*)d_in[7];
  const float* b_delta= (const float*)d_in[8];
  const float* w_B    = (const float*)d_in[9];
  const float* b_B    = (const float*)d_in[10];
  const float* w_C    = (const float*)d_in[11];
  const float* b_C    = (const float*)d_in[12];
  const float* w_out  = (const float*)d_in[13];
  const float* b_out  = (const float*)d_in[14];

  char* w = (char*)d_ws;
  u16* w_in_bf  = (u16*)w; w += (size_t)2 * 1024 * 1024 * 2;   // 4 MB
  u16* wcat_bf  = (u16*)w; w += (size_t)3 * 1024 * 1024 * 2;   // 6 MB (delta|B|C rows)
  u16* w_out_bf = (u16*)w; w += (size_t)1024 * 1024 * 2;       // 2 MB
  float* bcat   = (float*)w; w += 16384;                        // 3072 floats, padded
  u16* h_bf     = (u16*)w; w += (size_t)MROWS * 1024 * 2;      // 32 MB (later: G, then gg)
  u16* uv_bf    = (u16*)w; w += (size_t)MROWS * 2048 * 2;      // 64 MB
  u16* uc_bf    = (u16*)w; w += (size_t)MROWS * 1024 * 2;      // 32 MB
  u16* dbc_bf   = (u16*)w; w += (size_t)MROWS * 3072 * 2;      // 96 MB
  float* P      = (float*)w; w += (size_t)BATCH * NCHUNK * 1024 * 4;
  float* S      = (float*)w; w += (size_t)BATCH * NCHUNK * 1024 * 4;
  float* Hin    = (float*)w; w += (size_t)BATCH * NCHUNK * 1024 * 4;
  float* ylocal = (float*)w; w += (size_t)MROWS * 4;
  u16* gbuf     = h_bf;   // h dead after GEMM1; holds G (scanA), then gg (scanC gate)

  // fused weight prep + LN (one launch)
  prep_ln_kernel<<<6147 + MROWS, 256, 0, stream>>>(
      w_in, w_delta, w_B, w_C, w_out, b_delta, b_B, b_C,
      w_in_bf, wcat_bf, w_out_bf, bcat, x, ln_g, ln_b, h_bf);

  // in_proj: uv[16384,2048]
  gemm256<0><<<dim3((2048/256) * (MROWS/256)), 512, 0, stream>>>(
      h_bf, w_in_bf, b_in, uv_bf, nullptr, nullptr, 2048);

  conv_kernel<<<(MROWS / 16) * 128 / 256, 256, 0, stream>>>(uv_bf, w_conv, b_conv, uc_bf);

  // delta|B|C fused: dbc[16384,3072]
  gemm256<0><<<dim3((3072/256) * (MROWS/256)), 512, 0, stream>>>(
      uc_bf, wcat_bf, bcat, dbc_bf, nullptr, nullptr, 3072);

  scanA<<<BATCH * NCHUNK, 256, 0, stream>>>(dbc_bf, uc_bf, gbuf, P, S, ylocal);
  scanB<<<(BATCH * 1024 / 4) / 256, 256, 0, stream>>>(P, S, Hin);
  scanC<<<BATCH * NCHUNK, 256, 0, stream>>>(gbuf, Hin, ylocal, uv_bf);

  // out_proj + bias + residual -> d_out (fp32)
  gemm256<1><<<dim3((1024/256) * (MROWS/256)), 512, 0, stream>>>(
      gbuf, w_out_bf, b_out, nullptr, (float*)d_out, x, 1024);
}

// Round 13
// 342.152 us; speedup vs baseline: 1.0190x; 1.0190x over previous
//
#include <hip/hip_runtime.h>
#include <stdint.h>

#define D_MODEL 1024
#define KDIM 1024             // all three GEMMs have K=1024 (compile-time)
#define BATCH 4
#define SEQ 4096
#define MROWS (BATCH*SEQ)     // 16384
#define CHUNK 32
#define NCHUNK (SEQ/CHUNK)    // 128

typedef unsigned short u16;
typedef __attribute__((ext_vector_type(8))) short short8;
typedef __attribute__((ext_vector_type(4))) float f32x4;
typedef __attribute__((ext_vector_type(4))) unsigned short u16x4;

__device__ __forceinline__ u16 f2bf(float f){
  uint32_t b = __builtin_bit_cast(uint32_t, f);
  b += 0x7FFFu + ((b >> 16) & 1u);
  return (u16)(b >> 16);
}
__device__ __forceinline__ float bf2f(u16 u){
  uint32_t b = ((uint32_t)u) << 16;
  return __builtin_bit_cast(float, b);
}

// ---------------- fused prep (weights fp32->bf16 + bias concat) + layernorm ----------
__global__ __launch_bounds__(256) void prep_ln_kernel(
    const float* __restrict__ w_in, const float* __restrict__ w_delta,
    const float* __restrict__ w_B, const float* __restrict__ w_C,
    const float* __restrict__ w_out,
    const float* __restrict__ b_delta, const float* __restrict__ b_B,
    const float* __restrict__ b_C,
    u16* __restrict__ w_in_bf, u16* __restrict__ wcat_bf,
    u16* __restrict__ w_out_bf, float* __restrict__ bcat,
    const float* __restrict__ x, const float* __restrict__ g,
    const float* __restrict__ bb, u16* __restrict__ h){
  if (blockIdx.x >= 6147){
    // ---- LN ----
    int row = blockIdx.x - 6147;
    int tid = threadIdx.x, lane = tid & 63, wid = tid >> 6;
    const float* xr = x + (size_t)row * D_MODEL;
    float4 v = *(const float4*)(xr + tid * 4);
    float s  = v.x + v.y + v.z + v.w;
    float s2 = v.x*v.x + v.y*v.y + v.z*v.z + v.w*v.w;
#pragma unroll
    for (int off = 32; off > 0; off >>= 1){ s += __shfl_down(s, off); s2 += __shfl_down(s2, off); }
    __shared__ float red[8];
    if (lane == 0){ red[wid] = s; red[4 + wid] = s2; }
    __syncthreads();
    s  = red[0] + red[1] + red[2] + red[3];
    s2 = red[4] + red[5] + red[6] + red[7];
    float mu  = s * (1.f / D_MODEL);
    float var = s2 * (1.f / D_MODEL) - mu * mu;
    float rs  = rsqrtf(var + 1e-5f);
    int c = tid * 4;
    u16x4 o;
    o.x = f2bf((v.x - mu) * rs * g[c+0] + bb[c+0]);
    o.y = f2bf((v.y - mu) * rs * g[c+1] + bb[c+1]);
    o.z = f2bf((v.z - mu) * rs * g[c+2] + bb[c+2]);
    o.w = f2bf((v.w - mu) * rs * g[c+3] + bb[c+3]);
    *(u16x4*)(h + (size_t)row * D_MODEL + c) = o;
    return;
  }
  // ---- weight prep ----
  int i4 = blockIdx.x * 256 + threadIdx.x;   // 4-element units
  const float* src; u16* dst; int off;
  if      (i4 <  524288){ src = w_in;    dst = w_in_bf;           off = i4; }
  else if (i4 <  786432){ src = w_delta; dst = wcat_bf;           off = i4 -  524288; }
  else if (i4 < 1048576){ src = w_B;     dst = wcat_bf + 1048576; off = i4 -  786432; }
  else if (i4 < 1310720){ src = w_C;     dst = wcat_bf + 2097152; off = i4 - 1048576; }
  else if (i4 < 1572864){ src = w_out;   dst = w_out_bf;          off = i4 - 1310720; }
  else {
    int t = i4 - 1572864;    // 768 threads copy 3072 bias floats
    if      (t < 256){ *(float4*)(bcat +        t*4)        = *(const float4*)(b_delta + t*4); }
    else if (t < 512){ *(float4*)(bcat + 1024 + (t-256)*4)  = *(const float4*)(b_B + (t-256)*4); }
    else if (t < 768){ *(float4*)(bcat + 2048 + (t-512)*4)  = *(const float4*)(b_C + (t-512)*4); }
    return;
  }
  float4 v = *(const float4*)(src + (size_t)off * 4);
  u16x4 o; o.x = f2bf(v.x); o.y = f2bf(v.y); o.z = f2bf(v.z); o.w = f2bf(v.w);
  *(u16x4*)(dst + (size_t)off * 4) = o;
}

// ---------------- 256x256 bf16 MFMA GEMM, BK=32, ring-4, ONE barrier per K-tile ----
// EXACT R6 kernel (proven 103.4us dbc, 0 bank conflicts, 16x16x32 MFMA).
// R12's 32x32 variant re-introduced 4-way bank conflicts (9.4e6) — reverted.
// Swizzle: byte ^= ((row>>1)&3)<<4.  vmcnt(8) steady, drain 8/4/0.
// EPI 0: store bf16(out).  EPI 1: store fp32(out + resid).
#define VMCNT_(N) asm volatile("s_waitcnt vmcnt(" #N ")" ::: "memory")
#define VMCNT(N) VMCNT_(N)

template<int EPI>
__global__ __launch_bounds__(512, 2) void gemm256(
    const u16* __restrict__ A, const u16* __restrict__ W,
    const float* __restrict__ bias,
    u16* __restrict__ outb, float* __restrict__ outf,
    const float* __restrict__ resid, int N){
  __shared__ char lds[131072];   // A bufs: [0,64KB) ; B bufs: [64KB,128KB)
  const int tid = threadIdx.x, wid = tid >> 6, lane = tid & 63;
  const int wm = wid >> 2, wn = wid & 3;
  const int lrow = lane & 15, khi = lane >> 4;

  int nwg = gridDim.x;
  int cpx = nwg >> 3;
  int bid = blockIdx.x;
  int wg = (bid & 7) * cpx + (bid >> 3);
  int ntile = N >> 8;
  int by = wg / ntile, bx = wg % ntile;
  int m0 = by << 8, n0 = bx << 8;

  f32x4 acc[8][4];
  f32x4 zero = {0.f, 0.f, 0.f, 0.f};
#pragma unroll
  for (int i = 0; i < 8; i++)
#pragma unroll
    for (int j = 0; j < 4; j++) acc[i][j] = zero;

  const int xr = ((lrow >> 1) & 3) << 4;
  const int aOff = (wm * 128 + lrow) * 64 + ((khi * 16) ^ xr);
  const int bOff = (wn * 64  + lrow) * 64 + ((khi * 16) ^ xr);

  const int rS = tid >> 2;
  const int cbS = ((tid & 3) * 16) ^ (((rS >> 1) & 3) << 4);
  const u16* gA = A + (size_t)(m0 + rS) * KDIM + (cbS >> 1);
  const u16* gB = W + (size_t)(n0 + rS) * KDIM + (cbS >> 1);

  auto stA = [&](int kt, int bi){
    const u16* g0 = gA + kt;
    unsigned l0 = (unsigned)(bi * 16384 + wid * 1024);
    __builtin_amdgcn_global_load_lds((const __attribute__((address_space(1))) void*)g0,
                                     (__attribute__((address_space(3))) void*)(lds + l0), 16, 0, 0);
    __builtin_amdgcn_global_load_lds((const __attribute__((address_space(1))) void*)(g0 + 128 * KDIM),
                                     (__attribute__((address_space(3))) void*)(lds + l0 + 8192), 16, 0, 0);
  };
  auto stB = [&](int kt, int bi){
    const u16* g0 = gB + kt;
    unsigned l0 = (unsigned)(65536 + bi * 16384 + wid * 1024);
    __builtin_amdgcn_global_load_lds((const __attribute__((address_space(1))) void*)g0,
                                     (__attribute__((address_space(3))) void*)(lds + l0), 16, 0, 0);
    __builtin_amdgcn_global_load_lds((const __attribute__((address_space(1))) void*)(g0 + 128 * KDIM),
                                     (__attribute__((address_space(3))) void*)(lds + l0 + 8192), 16, 0, 0);
  };

#define TILE(BI, STKT, DOSTAGE, WAITC) { \
  const char* pa = lds + (BI) * 16384; \
  const char* pb = lds + 65536 + (BI) * 16384; \
  short8 bfr[4], afr[8]; \
  _Pragma("unroll") \
  for (int nf = 0; nf < 4; nf++) bfr[nf] = *(const short8*)(pb + bOff + nf * 1024); \
  _Pragma("unroll") \
  for (int mi = 0; mi < 8; mi++) afr[mi] = *(const short8*)(pa + aOff + mi * 1024); \
  if (DOSTAGE){ stA((STKT), ((BI) + 3) & 3); stB((STKT), ((BI) + 3) & 3); } \
  __builtin_amdgcn_sched_barrier(0); \
  __builtin_amdgcn_s_setprio(1); \
  _Pragma("unroll") \
  for (int mi = 0; mi < 8; mi++) \
    _Pragma("unroll") \
    for (int nf = 0; nf < 4; nf++) \
      acc[mi][nf] = __builtin_amdgcn_mfma_f32_16x16x32_bf16(afr[mi], bfr[nf], acc[mi][nf], 0, 0, 0); \
  __builtin_amdgcn_s_setprio(0); \
  WAITC; \
  __builtin_amdgcn_s_barrier(); \
}

  // prologue: stage tiles 0,1,2; wait tile 0 landed (8 still outstanding)
  stA(0, 0);  stB(0, 0);
  stA(32, 1); stB(32, 1);
  stA(64, 2); stB(64, 2);
  VMCNT(8);
  __builtin_amdgcn_s_barrier();

  // tiles 0..27: steady state (tile k stages tile k+3, end-wait vmcnt(8))
  for (int kk = 0; kk < 28; kk += 4){
    TILE(0, (kk + 3) << 5, 1, VMCNT(8));
    TILE(1, (kk + 4) << 5, 1, VMCNT(8));
    TILE(2, (kk + 5) << 5, 1, VMCNT(8));
    TILE(3, (kk + 6) << 5, 1, VMCNT(8));
  }
  // tile 28 stages tile 31; then drain
  TILE(0, 992, 1, VMCNT(8));
  TILE(1, 0, 0, VMCNT(4));
  TILE(2, 0, 0, VMCNT(0));
  TILE(3, 0, 0, (void)0);
#undef TILE

  // epilogue: D row = (lane>>4)*4 + i, col = lane&15 (m89-verified layout)
  float bv[4];
#pragma unroll
  for (int nf = 0; nf < 4; nf++) bv[nf] = bias[n0 + wn * 64 + nf * 16 + lrow];
#pragma unroll
  for (int mf = 0; mf < 8; mf++){
    int r0 = m0 + wm * 128 + mf * 16 + khi * 4;
#pragma unroll
    for (int nf = 0; nf < 4; nf++){
      int c = n0 + wn * 64 + nf * 16 + lrow;
#pragma unroll
      for (int i2 = 0; i2 < 4; i2++){
        float val = acc[mf][nf][i2] + bv[nf];
        size_t o = (size_t)(r0 + i2) * N + c;
        if (EPI == 0) outb[o] = f2bf(val);
        else          outf[o] = val + resid[o];
      }
    }
  }
}

// ---------------- depthwise causal conv1d (K=4), sliding-window ----------------
__global__ __launch_bounds__(256) void conv_kernel(const u16* __restrict__ uv,
    const float* __restrict__ wc, const float* __restrict__ bc, u16* __restrict__ uc){
  int idx = blockIdx.x * 256 + threadIdx.x;   // (MROWS/16) segs x 128 d-groups
  int d0 = (idx & 127) * 8;
  int m0 = (idx >> 7) * 16;
  int l0 = m0 & (SEQ - 1);
  float4 wv[8]; float bias[8];
#pragma unroll
  for (int j = 0; j < 8; j++){ wv[j] = *(const float4*)(wc + (d0 + j) * 4); bias[j] = bc[d0 + j]; }
  short8 zero8 = {0,0,0,0,0,0,0,0};
  short8 w0 = zero8, w1 = zero8, w2 = zero8;
  if (l0 > 0){
    w0 = *(const short8*)(uv + (size_t)(m0 - 3) * 2048 + d0);
    w1 = *(const short8*)(uv + (size_t)(m0 - 2) * 2048 + d0);
    w2 = *(const short8*)(uv + (size_t)(m0 - 1) * 2048 + d0);
  }
  const u16* pi = uv + (size_t)m0 * 2048 + d0;
  u16* po = uc + (size_t)m0 * 1024 + d0;
#pragma unroll 4
  for (int t = 0; t < 16; t++){
    short8 cur = *(const short8*)pi;  pi += 2048;
    short8 o;
#pragma unroll
    for (int j = 0; j < 8; j++){
      float a = bias[j] + bf2f((u16)w0[j]) * wv[j].x + bf2f((u16)w1[j]) * wv[j].y
                        + bf2f((u16)w2[j]) * wv[j].z + bf2f((u16)cur[j]) * wv[j].w;
      o[j] = (short)f2bf(a);
    }
    *(short8*)po = o;  po += 1024;
    w0 = w1; w1 = w2; w2 = cur;
  }
}

// ---------------- scan pass A: local scan + G=cumdec*C + y_local + P,S -------------
// CHUNK=32 -> grid 512 blocks (2 blocks/CU, 8 waves/CU; was 1 wave/SIMD at CHUNK=64).
__global__ __launch_bounds__(256) void scanA(const u16* __restrict__ dbc, const u16* __restrict__ uc,
                                             u16* __restrict__ G, float* __restrict__ P,
                                             float* __restrict__ S, float* __restrict__ ylocal){
  int b = blockIdx.x >> 7, c = blockIdx.x & (NCHUNK - 1);
  int tid = threadIdx.x, n0 = tid * 4;
  __shared__ float part[CHUNK][257];
  __shared__ float red2[CHUNK][9];
  size_t mbase = (size_t)b * SEQ + c * CHUNK;
  float Pv[4] = {1.f,1.f,1.f,1.f}, Sv[4] = {0.f,0.f,0.f,0.f};
  const u16* pd = dbc + mbase * 3072 + n0;
  const u16* pu = uc + mbase * 1024 + n0;
  u16* pg = G + mbase * 1024 + n0;
#pragma unroll 2
  for (int t = 0; t < CHUNK; t++){
    u16x4 dr = *(const u16x4*)pd;
    u16x4 bm = *(const u16x4*)(pd + 1024);
    u16x4 cm = *(const u16x4*)(pd + 2048);
    u16x4 uu = *(const u16x4*)pu;
    pd += 3072; pu += 1024;
    float contrib = 0.f;
    u16x4 go;
#pragma unroll
    for (int j = 0; j < 4; j++){
      float dec = 1.f / (1.f + __expf(bf2f(dr[j])));   // exp(-softplus) == sigmoid(-x)
      float cf = bf2f(cm[j]);
      Pv[j] *= dec;
      Sv[j] = Sv[j] * dec + bf2f(uu[j]) * bf2f(bm[j]);
      go[j] = f2bf(Pv[j] * cf);
      contrib += Sv[j] * cf;
    }
    *(u16x4*)pg = go;  pg += 1024;
    part[t][tid] = contrib;
  }
  __syncthreads();
  {
    int t = tid & (CHUNK - 1), q = tid >> 5;   // 32 t x 8 q
    float s = 0.f;
#pragma unroll
    for (int j = 0; j < 32; j++) s += part[t][q * 32 + j];
    red2[t][q] = s;
  }
  __syncthreads();
  if (tid < CHUNK){
    float s = 0.f;
#pragma unroll
    for (int q = 0; q < 8; q++) s += red2[tid][q];
    ylocal[mbase + tid] = s;
  }
  int o = (b * NCHUNK + c) * 1024 + n0;
  float4 p4 = {Pv[0], Pv[1], Pv[2], Pv[3]};
  float4 s4 = {Sv[0], Sv[1], Sv[2], Sv[3]};
  *(float4*)(P + o) = p4;
  *(float4*)(S + o) = s4;
}

// ---------------- pass B: chunk-level scan (float4) ----------------
__global__ void scanB(const float* __restrict__ P, const float* __restrict__ S,
                      float* __restrict__ Hin){
  int idx = blockIdx.x * 256 + threadIdx.x;  // 1024 threads
  int n0 = (idx & 255) * 4, b = idx >> 8;
  float4 H = {0.f,0.f,0.f,0.f};
  for (int c = 0; c < NCHUNK; c++){
    int o = (b * NCHUNK + c) * 1024 + n0;
    *(float4*)(Hin + o) = H;
    float4 p = *(const float4*)(P + o);
    float4 s = *(const float4*)(S + o);
    H.x = H.x * p.x + s.x;  H.y = H.y * p.y + s.y;
    H.z = H.z * p.z + s.z;  H.w = H.w * p.w + s.w;
  }
}

// ---------------- pass C': y = y_local + Hin.G  + fused gate ----------------------
__global__ __launch_bounds__(256) void scanC(u16* gbuf, const float* __restrict__ Hin,
                                             const float* __restrict__ ylocal,
                                             const u16* __restrict__ uv){
  int b = blockIdx.x >> 7, c = blockIdx.x & (NCHUNK - 1);
  int tid = threadIdx.x, n0 = tid * 4;
  __shared__ float part[CHUNK][257];
  __shared__ float red2[CHUNK][9];
  __shared__ float ys[CHUNK];
  size_t mbase = (size_t)b * SEQ + c * CHUNK;
  float4 h4 = *(const float4*)(Hin + (b * NCHUNK + c) * 1024 + n0);
  const u16* pG = gbuf + mbase * 1024 + n0;
#pragma unroll 4
  for (int t = 0; t < CHUNK; t++){
    u16x4 g = *(const u16x4*)pG;  pG += 1024;
    part[t][tid] = h4.x * bf2f(g.x) + h4.y * bf2f(g.y)
                 + h4.z * bf2f(g.z) + h4.w * bf2f(g.w);
  }
  __syncthreads();
  {
    int t = tid & (CHUNK - 1), q = tid >> 5;
    float s = 0.f;
#pragma unroll
    for (int j = 0; j < 32; j++) s += part[t][q * 32 + j];
    red2[t][q] = s;
  }
  __syncthreads();
  if (tid < CHUNK){
    float s = ylocal[mbase + tid];
#pragma unroll
    for (int q = 0; q < 8; q++) s += red2[tid][q];
    ys[tid] = s;
  }
  __syncthreads();
  // fused gate: gg[mbase+t][d] = bf16( y[t] * sigmoid(v[mbase+t][d]) ), overwrites G rows
  const u16* pv = uv + mbase * 2048 + 1024;
  u16* pg = gbuf + mbase * 1024;
#pragma unroll 4
  for (int i2 = 0; i2 < (CHUNK * 128) / 256; i2++){
    int e = i2 * 256 + tid;
    int t = e >> 7, ch = e & 127;
    short8 v = *(const short8*)(pv + (size_t)t * 2048 + ch * 8);
    float yv = ys[t];
    short8 o;
#pragma unroll
    for (int j = 0; j < 8; j++){
      float vf = bf2f((u16)v[j]);
      float sg = 1.f / (1.f + __expf(-vf));
      o[j] = (short)f2bf(yv * sg);
    }
    *(short8*)(pg + (size_t)t * 1024 + ch * 8) = o;
  }
}

extern "C" void kernel_launch(void* const* d_in, const int* in_sizes, int n_in,
                              void* d_out, int out_size, void* d_ws, size_t ws_size,
                              hipStream_t stream) {
  const float* x      = (const float*)d_in[0];
  const float* ln_g   = (const float*)d_in[1];
  const float* ln_b   = (const float*)d_in[2];
  const float* w_in   = (const float*)d_in[3];
  const float* b_in   = (const float*)d_in[4];
  const float* w_conv = (const float*)d_in[5];
  const float* b_conv = (const float*)d_in[6];
  const float* w_delta= (const float*)d_in[7];
  const float* b_delta= (const float*)d_in[8];
  const float* w_B    = (const float*)d_in[9];
  const float* b_B    = (const float*)d_in[10];
  const float* w_C    = (const float*)d_in[11];
  const float* b_C    = (const float*)d_in[12];
  const float* w_out  = (const float*)d_in[13];
  const float* b_out  = (const float*)d_in[14];

  char* w = (char*)d_ws;
  u16* w_in_bf  = (u16*)w; w += (size_t)2 * 1024 * 1024 * 2;   // 4 MB
  u16* wcat_bf  = (u16*)w; w += (size_t)3 * 1024 * 1024 * 2;   // 6 MB (delta|B|C rows)
  u16* w_out_bf = (u16*)w; w += (size_t)1024 * 1024 * 2;       // 2 MB
  float* bcat   = (float*)w; w += 16384;                        // 3072 floats, padded
  u16* h_bf     = (u16*)w; w += (size_t)MROWS * 1024 * 2;      // 32 MB (later: G, then gg)
  u16* uv_bf    = (u16*)w; w += (size_t)MROWS * 2048 * 2;      // 64 MB
  u16* uc_bf    = (u16*)w; w += (size_t)MROWS * 1024 * 2;      // 32 MB
  u16* dbc_bf   = (u16*)w; w += (size_t)MROWS * 3072 * 2;      // 96 MB
  float* P      = (float*)w; w += (size_t)BATCH * NCHUNK * 1024 * 4;   // 2 MB
  float* S      = (float*)w; w += (size_t)BATCH * NCHUNK * 1024 * 4;   // 2 MB
  float* Hin    = (float*)w; w += (size_t)BATCH * NCHUNK * 1024 * 4;   // 2 MB
  float* ylocal = (float*)w; w += (size_t)MROWS * 4;
  u16* gbuf     = h_bf;   // h dead after GEMM1; holds G (scanA), then gg (scanC gate)

  // fused weight prep + LN (one launch)
  prep_ln_kernel<<<6147 + MROWS, 256, 0, stream>>>(
      w_in, w_delta, w_B, w_C, w_out, b_delta, b_B, b_C,
      w_in_bf, wcat_bf, w_out_bf, bcat, x, ln_g, ln_b, h_bf);

  // in_proj: uv[16384,2048]
  gemm256<0><<<dim3((2048/256) * (MROWS/256)), 512, 0, stream>>>(
      h_bf, w_in_bf, b_in, uv_bf, nullptr, nullptr, 2048);

  conv_kernel<<<(MROWS / 16) * 128 / 256, 256, 0, stream>>>(uv_bf, w_conv, b_conv, uc_bf);

  // delta|B|C fused: dbc[16384,3072]
  gemm256<0><<<dim3((3072/256) * (MROWS/256)), 512, 0, stream>>>(
      uc_bf, wcat_bf, bcat, dbc_bf, nullptr, nullptr, 3072);

  scanA<<<BATCH * NCHUNK, 256, 0, stream>>>(dbc_bf, uc_bf, gbuf, P, S, ylocal);
  scanB<<<(BATCH * 1024 / 4) / 256, 256, 0, stream>>>(P, S, Hin);
  scanC<<<BATCH * NCHUNK, 256, 0, stream>>>(gbuf, Hin, ylocal, uv_bf);

  // out_proj + bias + residual -> d_out (fp32)
  gemm256<1><<<dim3((1024/256) * (MROWS/256)), 512, 0, stream>>>(
      gbuf, w_out_bf, b_out, nullptr, (float*)d_out, x, 1024);
}

// Round 14
// 320.990 us; speedup vs baseline: 1.0862x; 1.0659x over previous
//
#include <hip/hip_runtime.h>
#include <stdint.h>

#define D_MODEL 1024
#define KDIM 1024
#define BATCH 4
#define SEQ 4096
#define MROWS (BATCH*SEQ)     // 16384
#define CHUNK 64
#define NCHUNK (SEQ/CHUNK)    // 64

typedef unsigned short u16;
typedef __attribute__((ext_vector_type(8))) short short8;
typedef __attribute__((ext_vector_type(4))) float f32x4;
typedef __attribute__((ext_vector_type(4))) unsigned short u16x4;

__device__ __forceinline__ u16 f2bf(float f){
  uint32_t b = __builtin_bit_cast(uint32_t, f);
  b += 0x7FFFu + ((b >> 16) & 1u);
  return (u16)(b >> 16);
}
__device__ __forceinline__ float bf2f(u16 u){
  uint32_t b = ((uint32_t)u) << 16;
  return __builtin_bit_cast(float, b);
}

// ---------------- fused prep (weights fp32->bf16 + bias concat) + layernorm ----------
__global__ __launch_bounds__(256) void prep_ln_kernel(
    const float* __restrict__ w_in, const float* __restrict__ w_delta,
    const float* __restrict__ w_B, const float* __restrict__ w_C,
    const float* __restrict__ w_out,
    const float* __restrict__ b_delta, const float* __restrict__ b_B,
    const float* __restrict__ b_C,
    u16* __restrict__ w_in_bf, u16* __restrict__ wcat_bf,
    u16* __restrict__ w_out_bf, float* __restrict__ bcat,
    const float* __restrict__ x, const float* __restrict__ g,
    const float* __restrict__ bb, u16* __restrict__ h){
  if (blockIdx.x >= 6147){
    // ---- LN ----
    int row = blockIdx.x - 6147;
    int tid = threadIdx.x, lane = tid & 63, wid = tid >> 6;
    const float* xr = x + (size_t)row * D_MODEL;
    float4 v = *(const float4*)(xr + tid * 4);
    float s  = v.x + v.y + v.z + v.w;
    float s2 = v.x*v.x + v.y*v.y + v.z*v.z + v.w*v.w;
#pragma unroll
    for (int off = 32; off > 0; off >>= 1){ s += __shfl_down(s, off); s2 += __shfl_down(s2, off); }
    __shared__ float red[8];
    if (lane == 0){ red[wid] = s; red[4 + wid] = s2; }
    __syncthreads();
    s  = red[0] + red[1] + red[2] + red[3];
    s2 = red[4] + red[5] + red[6] + red[7];
    float mu  = s * (1.f / D_MODEL);
    float var = s2 * (1.f / D_MODEL) - mu * mu;
    float rs  = rsqrtf(var + 1e-5f);
    int c = tid * 4;
    u16x4 o;
    o.x = f2bf((v.x - mu) * rs * g[c+0] + bb[c+0]);
    o.y = f2bf((v.y - mu) * rs * g[c+1] + bb[c+1]);
    o.z = f2bf((v.z - mu) * rs * g[c+2] + bb[c+2]);
    o.w = f2bf((v.w - mu) * rs * g[c+3] + bb[c+3]);
    *(u16x4*)(h + (size_t)row * D_MODEL + c) = o;
    return;
  }
  // ---- weight prep ----
  int i4 = blockIdx.x * 256 + threadIdx.x;   // 4-element units
  const float* src; u16* dst; int off;
  if      (i4 <  524288){ src = w_in;    dst = w_in_bf;           off = i4; }
  else if (i4 <  786432){ src = w_delta; dst = wcat_bf;           off = i4 -  524288; }
  else if (i4 < 1048576){ src = w_B;     dst = wcat_bf + 1048576; off = i4 -  786432; }
  else if (i4 < 1310720){ src = w_C;     dst = wcat_bf + 2097152; off = i4 - 1048576; }
  else if (i4 < 1572864){ src = w_out;   dst = w_out_bf;          off = i4 - 1310720; }
  else {
    int t = i4 - 1572864;    // 768 threads copy 3072 bias floats
    if      (t < 256){ *(float4*)(bcat +        t*4)        = *(const float4*)(b_delta + t*4); }
    else if (t < 512){ *(float4*)(bcat + 1024 + (t-256)*4)  = *(const float4*)(b_B + (t-256)*4); }
    else if (t < 768){ *(float4*)(bcat + 2048 + (t-512)*4)  = *(const float4*)(b_C + (t-512)*4); }
    return;
  }
  float4 v = *(const float4*)(src + (size_t)off * 4);
  u16x4 o; o.x = f2bf(v.x); o.y = f2bf(v.y); o.z = f2bf(v.z); o.w = f2bf(v.w);
  *(u16x4*)(dst + (size_t)off * 4) = o;
}

// ---------------- 256x256 bf16 MFMA GEMM, BK=32, ring-4, ONE barrier per K-tile ----
// EXACT R6 schedule (proven 103.4us dbc, 0 bank conflicts, 16x16x32 MFMA).
// Swizzle: byte ^= ((row>>1)&3)<<4.  vmcnt(8) steady, drain 8/4/0.
// NEW plumbing only: lda (A row stride, elements); SIG: apply sigmoid to
// cols >= 1024 (in_proj v-half); EPI 1: fp32 out = acc*yv[row] + bias + resid.
#define VMCNT_(N) asm volatile("s_waitcnt vmcnt(" #N ")" ::: "memory")
#define VMCNT(N) VMCNT_(N)

template<int EPI, int SIG>
__global__ __launch_bounds__(512, 2) void gemm256(
    const u16* __restrict__ A, const u16* __restrict__ W,
    const float* __restrict__ bias,
    u16* __restrict__ outb, float* __restrict__ outf,
    const float* __restrict__ resid, const float* __restrict__ yv,
    int N, int lda){
  __shared__ char lds[131072];   // A bufs: [0,64KB) ; B bufs: [64KB,128KB)
  const int tid = threadIdx.x, wid = tid >> 6, lane = tid & 63;
  const int wm = wid >> 2, wn = wid & 3;
  const int lrow = lane & 15, khi = lane >> 4;

  int nwg = gridDim.x;
  int cpx = nwg >> 3;
  int bid = blockIdx.x;
  int wg = (bid & 7) * cpx + (bid >> 3);
  int ntile = N >> 8;
  int by = wg / ntile, bx = wg % ntile;
  int m0 = by << 8, n0 = bx << 8;

  f32x4 acc[8][4];
  f32x4 zero = {0.f, 0.f, 0.f, 0.f};
#pragma unroll
  for (int i = 0; i < 8; i++)
#pragma unroll
    for (int j = 0; j < 4; j++) acc[i][j] = zero;

  const int xr = ((lrow >> 1) & 3) << 4;
  const int aOff = (wm * 128 + lrow) * 64 + ((khi * 16) ^ xr);
  const int bOff = (wn * 64  + lrow) * 64 + ((khi * 16) ^ xr);

  const int rS = tid >> 2;
  const int cbS = ((tid & 3) * 16) ^ (((rS >> 1) & 3) << 4);
  const u16* gA = A + (size_t)(m0 + rS) * lda + (cbS >> 1);
  const u16* gB = W + (size_t)(n0 + rS) * KDIM + (cbS >> 1);

  auto stA = [&](int kt, int bi){
    const u16* g0 = gA + kt;
    unsigned l0 = (unsigned)(bi * 16384 + wid * 1024);
    __builtin_amdgcn_global_load_lds((const __attribute__((address_space(1))) void*)g0,
                                     (__attribute__((address_space(3))) void*)(lds + l0), 16, 0, 0);
    __builtin_amdgcn_global_load_lds((const __attribute__((address_space(1))) void*)(g0 + (size_t)128 * lda),
                                     (__attribute__((address_space(3))) void*)(lds + l0 + 8192), 16, 0, 0);
  };
  auto stB = [&](int kt, int bi){
    const u16* g0 = gB + kt;
    unsigned l0 = (unsigned)(65536 + bi * 16384 + wid * 1024);
    __builtin_amdgcn_global_load_lds((const __attribute__((address_space(1))) void*)g0,
                                     (__attribute__((address_space(3))) void*)(lds + l0), 16, 0, 0);
    __builtin_amdgcn_global_load_lds((const __attribute__((address_space(1))) void*)(g0 + 128 * KDIM),
                                     (__attribute__((address_space(3))) void*)(lds + l0 + 8192), 16, 0, 0);
  };

#define TILE(BI, STKT, DOSTAGE, WAITC) { \
  const char* pa = lds + (BI) * 16384; \
  const char* pb = lds + 65536 + (BI) * 16384; \
  short8 bfr[4], afr[8]; \
  _Pragma("unroll") \
  for (int nf = 0; nf < 4; nf++) bfr[nf] = *(const short8*)(pb + bOff + nf * 1024); \
  _Pragma("unroll") \
  for (int mi = 0; mi < 8; mi++) afr[mi] = *(const short8*)(pa + aOff + mi * 1024); \
  if (DOSTAGE){ stA((STKT), ((BI) + 3) & 3); stB((STKT), ((BI) + 3) & 3); } \
  __builtin_amdgcn_sched_barrier(0); \
  __builtin_amdgcn_s_setprio(1); \
  _Pragma("unroll") \
  for (int mi = 0; mi < 8; mi++) \
    _Pragma("unroll") \
    for (int nf = 0; nf < 4; nf++) \
      acc[mi][nf] = __builtin_amdgcn_mfma_f32_16x16x32_bf16(afr[mi], bfr[nf], acc[mi][nf], 0, 0, 0); \
  __builtin_amdgcn_s_setprio(0); \
  WAITC; \
  __builtin_amdgcn_s_barrier(); \
}

  // prologue: stage tiles 0,1,2; wait tile 0 landed (8 still outstanding)
  stA(0, 0);  stB(0, 0);
  stA(32, 1); stB(32, 1);
  stA(64, 2); stB(64, 2);
  VMCNT(8);
  __builtin_amdgcn_s_barrier();

  // tiles 0..27: steady state (tile k stages tile k+3, end-wait vmcnt(8))
  for (int kk = 0; kk < 28; kk += 4){
    TILE(0, (kk + 3) << 5, 1, VMCNT(8));
    TILE(1, (kk + 4) << 5, 1, VMCNT(8));
    TILE(2, (kk + 5) << 5, 1, VMCNT(8));
    TILE(3, (kk + 6) << 5, 1, VMCNT(8));
  }
  // tile 28 stages tile 31; then drain
  TILE(0, 992, 1, VMCNT(8));
  TILE(1, 0, 0, VMCNT(4));
  TILE(2, 0, 0, VMCNT(0));
  TILE(3, 0, 0, (void)0);
#undef TILE

  // epilogue: D row = (lane>>4)*4 + i, col = lane&15 (m89-verified layout)
  float bv[4];
#pragma unroll
  for (int nf = 0; nf < 4; nf++) bv[nf] = bias[n0 + wn * 64 + nf * 16 + lrow];
  const bool dosig = SIG && (n0 >= 1024);
#pragma unroll
  for (int mf = 0; mf < 8; mf++){
    int r0 = m0 + wm * 128 + mf * 16 + khi * 4;
#pragma unroll
    for (int nf = 0; nf < 4; nf++){
      int c = n0 + wn * 64 + nf * 16 + lrow;
#pragma unroll
      for (int i2 = 0; i2 < 4; i2++){
        float val = acc[mf][nf][i2] + bv[nf];
        size_t o = (size_t)(r0 + i2) * N + c;
        if (EPI == 0){
          if (SIG && dosig) val = 1.f / (1.f + __expf(-val));
          outb[o] = f2bf(val);
        } else {
          float yrow = yv[r0 + i2];
          outf[o] = acc[mf][nf][i2] * yrow + bv[nf] + resid[o];
        }
      }
    }
  }
}

// ---------------- depthwise causal conv1d (K=4), sliding-window ----------------
__global__ __launch_bounds__(256) void conv_kernel(const u16* __restrict__ uv,
    const float* __restrict__ wc, const float* __restrict__ bc, u16* __restrict__ uc){
  int idx = blockIdx.x * 256 + threadIdx.x;   // (MROWS/16) segs x 128 d-groups
  int d0 = (idx & 127) * 8;
  int m0 = (idx >> 7) * 16;
  int l0 = m0 & (SEQ - 1);
  float4 wv[8]; float bias[8];
#pragma unroll
  for (int j = 0; j < 8; j++){ wv[j] = *(const float4*)(wc + (d0 + j) * 4); bias[j] = bc[d0 + j]; }
  short8 zero8 = {0,0,0,0,0,0,0,0};
  short8 w0 = zero8, w1 = zero8, w2 = zero8;
  if (l0 > 0){
    w0 = *(const short8*)(uv + (size_t)(m0 - 3) * 2048 + d0);
    w1 = *(const short8*)(uv + (size_t)(m0 - 2) * 2048 + d0);
    w2 = *(const short8*)(uv + (size_t)(m0 - 1) * 2048 + d0);
  }
  const u16* pi = uv + (size_t)m0 * 2048 + d0;
  u16* po = uc + (size_t)m0 * 1024 + d0;
#pragma unroll 4
  for (int t = 0; t < 16; t++){
    short8 cur = *(const short8*)pi;  pi += 2048;
    short8 o;
#pragma unroll
    for (int j = 0; j < 8; j++){
      float a = bias[j] + bf2f((u16)w0[j]) * wv[j].x + bf2f((u16)w1[j]) * wv[j].y
                        + bf2f((u16)w2[j]) * wv[j].z + bf2f((u16)cur[j]) * wv[j].w;
      o[j] = (short)f2bf(a);
    }
    *(short8*)po = o;  po += 1024;
    w0 = w1; w1 = w2; w2 = cur;
  }
}

// ---------------- scan pass A: local scan + G=cumdec*C + y_local + P,S (R11) -------
__global__ __launch_bounds__(256) void scanA(const u16* __restrict__ dbc, const u16* __restrict__ uc,
                                             u16* __restrict__ G, float* __restrict__ P,
                                             float* __restrict__ S, float* __restrict__ ylocal){
  int b = blockIdx.x >> 6, c = blockIdx.x & (NCHUNK - 1);
  int tid = threadIdx.x, n0 = tid * 4;
  __shared__ float part[CHUNK][257];
  __shared__ float red2[CHUNK][5];
  size_t mbase = (size_t)b * SEQ + c * CHUNK;
  float Pv[4] = {1.f,1.f,1.f,1.f}, Sv[4] = {0.f,0.f,0.f,0.f};
  const u16* pd = dbc + mbase * 3072 + n0;
  const u16* pu = uc + mbase * 1024 + n0;
  u16* pg = G + mbase * 1024 + n0;
#pragma unroll 2
  for (int t = 0; t < CHUNK; t++){
    u16x4 dr = *(const u16x4*)pd;
    u16x4 bm = *(const u16x4*)(pd + 1024);
    u16x4 cm = *(const u16x4*)(pd + 2048);
    u16x4 uu = *(const u16x4*)pu;
    pd += 3072; pu += 1024;
    float contrib = 0.f;
    u16x4 go;
#pragma unroll
    for (int j = 0; j < 4; j++){
      float dec = 1.f / (1.f + __expf(bf2f(dr[j])));   // exp(-softplus) == sigmoid(-x)
      float cf = bf2f(cm[j]);
      Pv[j] *= dec;
      Sv[j] = Sv[j] * dec + bf2f(uu[j]) * bf2f(bm[j]);
      go[j] = f2bf(Pv[j] * cf);
      contrib += Sv[j] * cf;
    }
    *(u16x4*)pg = go;  pg += 1024;
    part[t][tid] = contrib;
  }
  __syncthreads();
  {
    int t = tid & 63, q = tid >> 6;
    float s = 0.f;
#pragma unroll
    for (int j = 0; j < 64; j++) s += part[t][q * 64 + j];
    red2[t][q] = s;
  }
  __syncthreads();
  if (tid < CHUNK)
    ylocal[mbase + tid] = red2[tid][0] + red2[tid][1] + red2[tid][2] + red2[tid][3];
  int o = (b * NCHUNK + c) * 1024 + n0;
  float4 p4 = {Pv[0], Pv[1], Pv[2], Pv[3]};
  float4 s4 = {Sv[0], Sv[1], Sv[2], Sv[3]};
  *(float4*)(P + o) = p4;
  *(float4*)(S + o) = s4;
}

// ---------------- pass B: chunk-level scan (float4) ----------------
__global__ void scanB(const float* __restrict__ P, const float* __restrict__ S,
                      float* __restrict__ Hin){
  int idx = blockIdx.x * 256 + threadIdx.x;  // 1024 threads
  int n0 = (idx & 255) * 4, b = idx >> 8;
  float4 H = {0.f,0.f,0.f,0.f};
  for (int c = 0; c < NCHUNK; c++){
    int o = (b * NCHUNK + c) * 1024 + n0;
    *(float4*)(Hin + o) = H;
    float4 p = *(const float4*)(P + o);
    float4 s = *(const float4*)(S + o);
    H.x = H.x * p.x + s.x;  H.y = H.y * p.y + s.y;
    H.z = H.z * p.z + s.z;  H.w = H.w * p.w + s.w;
  }
}

// ---------------- pass C': ys = y_local + Hin.G  (gate removed — folded into GEMMs) --
__global__ __launch_bounds__(256) void scanC(const u16* __restrict__ G, const float* __restrict__ Hin,
                                             const float* __restrict__ ylocal, float* __restrict__ ysg){
  int b = blockIdx.x >> 6, c = blockIdx.x & (NCHUNK - 1);
  int tid = threadIdx.x, n0 = tid * 4;
  __shared__ float part[CHUNK][257];
  __shared__ float red2[CHUNK][5];
  size_t mbase = (size_t)b * SEQ + c * CHUNK;
  float4 h4 = *(const float4*)(Hin + (b * NCHUNK + c) * 1024 + n0);
  const u16* pG = G + mbase * 1024 + n0;
#pragma unroll 4
  for (int t = 0; t < CHUNK; t++){
    u16x4 g = *(const u16x4*)pG;  pG += 1024;
    part[t][tid] = h4.x * bf2f(g.x) + h4.y * bf2f(g.y)
                 + h4.z * bf2f(g.z) + h4.w * bf2f(g.w);
  }
  __syncthreads();
  {
    int t = tid & 63, q = tid >> 6;
    float s = 0.f;
#pragma unroll
    for (int j = 0; j < 64; j++) s += part[t][q * 64 + j];
    red2[t][q] = s;
  }
  __syncthreads();
  if (tid < CHUNK)
    ysg[mbase + tid] = red2[tid][0] + red2[tid][1] + red2[tid][2] + red2[tid][3]
                     + ylocal[mbase + tid];
}

extern "C" void kernel_launch(void* const* d_in, const int* in_sizes, int n_in,
                              void* d_out, int out_size, void* d_ws, size_t ws_size,
                              hipStream_t stream) {
  const float* x      = (const float*)d_in[0];
  const float* ln_g   = (const float*)d_in[1];
  const float* ln_b   = (const float*)d_in[2];
  const float* w_in   = (const float*)d_in[3];
  const float* b_in   = (const float*)d_in[4];
  const float* w_conv = (const float*)d_in[5];
  const float* b_conv = (const float*)d_in[6];
  const float* w_delta= (const float*)d_in[7];
  const float* b_delta= (const float*)d_in[8];
  const float* w_B    = (const float*)d_in[9];
  const float* b_B    = (const float*)d_in[10];
  const float* w_C    = (const float*)d_in[11];
  const float* b_C    = (const float*)d_in[12];
  const float* w_out  = (const float*)d_in[13];
  const float* b_out  = (const float*)d_in[14];

  char* w = (char*)d_ws;
  u16* w_in_bf  = (u16*)w; w += (size_t)2 * 1024 * 1024 * 2;   // 4 MB
  u16* wcat_bf  = (u16*)w; w += (size_t)3 * 1024 * 1024 * 2;   // 6 MB (delta|B|C rows)
  u16* w_out_bf = (u16*)w; w += (size_t)1024 * 1024 * 2;       // 2 MB
  float* bcat   = (float*)w; w += 16384;                        // 3072 floats, padded
  u16* h_bf     = (u16*)w; w += (size_t)MROWS * 1024 * 2;      // 32 MB (later holds G)
  u16* uv_bf    = (u16*)w; w += (size_t)MROWS * 2048 * 2;      // 64 MB (v-half stored as sigma(v))
  u16* uc_bf    = (u16*)w; w += (size_t)MROWS * 1024 * 2;      // 32 MB
  u16* dbc_bf   = (u16*)w; w += (size_t)MROWS * 3072 * 2;      // 96 MB
  float* P      = (float*)w; w += (size_t)BATCH * NCHUNK * 1024 * 4;
  float* S      = (float*)w; w += (size_t)BATCH * NCHUNK * 1024 * 4;
  float* Hin    = (float*)w; w += (size_t)BATCH * NCHUNK * 1024 * 4;
  float* ylocal = (float*)w; w += (size_t)MROWS * 4;
  float* ysg    = (float*)w; w += (size_t)MROWS * 4;
  u16* gbuf     = h_bf;   // h dead after GEMM1; holds G

  // fused weight prep + LN (one launch)
  prep_ln_kernel<<<6147 + MROWS, 256, 0, stream>>>(
      w_in, w_delta, w_B, w_C, w_out, b_delta, b_B, b_C,
      w_in_bf, wcat_bf, w_out_bf, bcat, x, ln_g, ln_b, h_bf);

  // in_proj: uv[16384,2048]; v-half (cols>=1024) stored as sigma(v)
  gemm256<0,1><<<dim3((2048/256) * (MROWS/256)), 512, 0, stream>>>(
      h_bf, w_in_bf, b_in, uv_bf, nullptr, nullptr, nullptr, 2048, 1024);

  conv_kernel<<<(MROWS / 16) * 128 / 256, 256, 0, stream>>>(uv_bf, w_conv, b_conv, uc_bf);

  // delta|B|C fused: dbc[16384,3072]
  gemm256<0,0><<<dim3((3072/256) * (MROWS/256)), 512, 0, stream>>>(
      uc_bf, wcat_bf, bcat, dbc_bf, nullptr, nullptr, nullptr, 3072, 1024);

  scanA<<<BATCH * NCHUNK, 256, 0, stream>>>(dbc_bf, uc_bf, gbuf, P, S, ylocal);
  scanB<<<(BATCH * 1024 / 4) / 256, 256, 0, stream>>>(P, S, Hin);
  scanC<<<BATCH * NCHUNK, 256, 0, stream>>>(gbuf, Hin, ylocal, ysg);

  // out_proj: A = sigma(v) half of uv (lda=2048); epilogue scales by ys[row],
  // adds bias + residual -> d_out (fp32)
  gemm256<1,0><<<dim3((1024/256) * (MROWS/256)), 512, 0, stream>>>(
      uv_bf + 1024, w_out_bf, b_out, nullptr, (float*)d_out, x, ysg, 1024, 2048);
}

// Round 15
// 318.488 us; speedup vs baseline: 1.0947x; 1.0079x over previous
//
#include <hip/hip_runtime.h>
#include <stdint.h>

#define D_MODEL 1024
#define KDIM 1024
#define BATCH 4
#define SEQ 4096
#define MROWS (BATCH*SEQ)     // 16384
#define CHUNK 64
#define NCHUNK (SEQ/CHUNK)    // 64

typedef unsigned short u16;
typedef __attribute__((ext_vector_type(8))) short short8;
typedef __attribute__((ext_vector_type(4))) float f32x4;
typedef __attribute__((ext_vector_type(2))) float f32x2;
typedef __attribute__((ext_vector_type(4))) unsigned short u16x4;
typedef __attribute__((ext_vector_type(2))) unsigned short u16x2;

__device__ __forceinline__ u16 f2bf(float f){
  uint32_t b = __builtin_bit_cast(uint32_t, f);
  b += 0x7FFFu + ((b >> 16) & 1u);
  return (u16)(b >> 16);
}
__device__ __forceinline__ float bf2f(u16 u){
  uint32_t b = ((uint32_t)u) << 16;
  return __builtin_bit_cast(float, b);
}

// ---------------- fused prep (weights fp32->bf16 + bias concat) + layernorm ----------
__global__ __launch_bounds__(256) void prep_ln_kernel(
    const float* __restrict__ w_in, const float* __restrict__ w_delta,
    const float* __restrict__ w_B, const float* __restrict__ w_C,
    const float* __restrict__ w_out,
    const float* __restrict__ b_delta, const float* __restrict__ b_B,
    const float* __restrict__ b_C,
    u16* __restrict__ w_in_bf, u16* __restrict__ wcat_bf,
    u16* __restrict__ w_out_bf, float* __restrict__ bcat,
    const float* __restrict__ x, const float* __restrict__ g,
    const float* __restrict__ bb, u16* __restrict__ h){
  if (blockIdx.x >= 6147){
    // ---- LN ----
    int row = blockIdx.x - 6147;
    int tid = threadIdx.x, lane = tid & 63, wid = tid >> 6;
    const float* xr = x + (size_t)row * D_MODEL;
    float4 v = *(const float4*)(xr + tid * 4);
    float s  = v.x + v.y + v.z + v.w;
    float s2 = v.x*v.x + v.y*v.y + v.z*v.z + v.w*v.w;
#pragma unroll
    for (int off = 32; off > 0; off >>= 1){ s += __shfl_down(s, off); s2 += __shfl_down(s2, off); }
    __shared__ float red[8];
    if (lane == 0){ red[wid] = s; red[4 + wid] = s2; }
    __syncthreads();
    s  = red[0] + red[1] + red[2] + red[3];
    s2 = red[4] + red[5] + red[6] + red[7];
    float mu  = s * (1.f / D_MODEL);
    float var = s2 * (1.f / D_MODEL) - mu * mu;
    float rs  = rsqrtf(var + 1e-5f);
    int c = tid * 4;
    u16x4 o;
    o.x = f2bf((v.x - mu) * rs * g[c+0] + bb[c+0]);
    o.y = f2bf((v.y - mu) * rs * g[c+1] + bb[c+1]);
    o.z = f2bf((v.z - mu) * rs * g[c+2] + bb[c+2]);
    o.w = f2bf((v.w - mu) * rs * g[c+3] + bb[c+3]);
    *(u16x4*)(h + (size_t)row * D_MODEL + c) = o;
    return;
  }
  // ---- weight prep ----
  int i4 = blockIdx.x * 256 + threadIdx.x;   // 4-element units
  const float* src; u16* dst; int off;
  if      (i4 <  524288){ src = w_in;    dst = w_in_bf;           off = i4; }
  else if (i4 <  786432){ src = w_delta; dst = wcat_bf;           off = i4 -  524288; }
  else if (i4 < 1048576){ src = w_B;     dst = wcat_bf + 1048576; off = i4 -  786432; }
  else if (i4 < 1310720){ src = w_C;     dst = wcat_bf + 2097152; off = i4 - 1048576; }
  else if (i4 < 1572864){ src = w_out;   dst = w_out_bf;          off = i4 - 1310720; }
  else {
    int t = i4 - 1572864;    // 768 threads copy 3072 bias floats
    if      (t < 256){ *(float4*)(bcat +        t*4)        = *(const float4*)(b_delta + t*4); }
    else if (t < 512){ *(float4*)(bcat + 1024 + (t-256)*4)  = *(const float4*)(b_B + (t-256)*4); }
    else if (t < 768){ *(float4*)(bcat + 2048 + (t-512)*4)  = *(const float4*)(b_C + (t-512)*4); }
    return;
  }
  float4 v = *(const float4*)(src + (size_t)off * 4);
  u16x4 o; o.x = f2bf(v.x); o.y = f2bf(v.y); o.z = f2bf(v.z); o.w = f2bf(v.w);
  *(u16x4*)(dst + (size_t)off * 4) = o;
}

// ---------------- 256x256 bf16 MFMA GEMM, BK=32, ring-4, ONE barrier per K-tile ----
// EXACT R6 schedule (proven 103.4us dbc, 0 bank conflicts, 16x16x32 MFMA).
// Swizzle: byte ^= ((row>>1)&3)<<4.  vmcnt(8) steady, drain 8/4/0.
// lda = A row stride; SIG: sigmoid on cols >= 1024 (in_proj v-half);
// EPI 1: fp32 out = acc*(yv[r]+yv[MROWS+r]) + bias + resid  (split-y halves).
#define VMCNT_(N) asm volatile("s_waitcnt vmcnt(" #N ")" ::: "memory")
#define VMCNT(N) VMCNT_(N)

template<int EPI, int SIG>
__global__ __launch_bounds__(512, 2) void gemm256(
    const u16* __restrict__ A, const u16* __restrict__ W,
    const float* __restrict__ bias,
    u16* __restrict__ outb, float* __restrict__ outf,
    const float* __restrict__ resid, const float* __restrict__ yv,
    int N, int lda){
  __shared__ char lds[131072];   // A bufs: [0,64KB) ; B bufs: [64KB,128KB)
  const int tid = threadIdx.x, wid = tid >> 6, lane = tid & 63;
  const int wm = wid >> 2, wn = wid & 3;
  const int lrow = lane & 15, khi = lane >> 4;

  int nwg = gridDim.x;
  int cpx = nwg >> 3;
  int bid = blockIdx.x;
  int wg = (bid & 7) * cpx + (bid >> 3);
  int ntile = N >> 8;
  int by = wg / ntile, bx = wg % ntile;
  int m0 = by << 8, n0 = bx << 8;

  f32x4 acc[8][4];
  f32x4 zero = {0.f, 0.f, 0.f, 0.f};
#pragma unroll
  for (int i = 0; i < 8; i++)
#pragma unroll
    for (int j = 0; j < 4; j++) acc[i][j] = zero;

  const int xr = ((lrow >> 1) & 3) << 4;
  const int aOff = (wm * 128 + lrow) * 64 + ((khi * 16) ^ xr);
  const int bOff = (wn * 64  + lrow) * 64 + ((khi * 16) ^ xr);

  const int rS = tid >> 2;
  const int cbS = ((tid & 3) * 16) ^ (((rS >> 1) & 3) << 4);
  const u16* gA = A + (size_t)(m0 + rS) * lda + (cbS >> 1);
  const u16* gB = W + (size_t)(n0 + rS) * KDIM + (cbS >> 1);

  auto stA = [&](int kt, int bi){
    const u16* g0 = gA + kt;
    unsigned l0 = (unsigned)(bi * 16384 + wid * 1024);
    __builtin_amdgcn_global_load_lds((const __attribute__((address_space(1))) void*)g0,
                                     (__attribute__((address_space(3))) void*)(lds + l0), 16, 0, 0);
    __builtin_amdgcn_global_load_lds((const __attribute__((address_space(1))) void*)(g0 + (size_t)128 * lda),
                                     (__attribute__((address_space(3))) void*)(lds + l0 + 8192), 16, 0, 0);
  };
  auto stB = [&](int kt, int bi){
    const u16* g0 = gB + kt;
    unsigned l0 = (unsigned)(65536 + bi * 16384 + wid * 1024);
    __builtin_amdgcn_global_load_lds((const __attribute__((address_space(1))) void*)g0,
                                     (__attribute__((address_space(3))) void*)(lds + l0), 16, 0, 0);
    __builtin_amdgcn_global_load_lds((const __attribute__((address_space(1))) void*)(g0 + 128 * KDIM),
                                     (__attribute__((address_space(3))) void*)(lds + l0 + 8192), 16, 0, 0);
  };

#define TILE(BI, STKT, DOSTAGE, WAITC) { \
  const char* pa = lds + (BI) * 16384; \
  const char* pb = lds + 65536 + (BI) * 16384; \
  short8 bfr[4], afr[8]; \
  _Pragma("unroll") \
  for (int nf = 0; nf < 4; nf++) bfr[nf] = *(const short8*)(pb + bOff + nf * 1024); \
  _Pragma("unroll") \
  for (int mi = 0; mi < 8; mi++) afr[mi] = *(const short8*)(pa + aOff + mi * 1024); \
  if (DOSTAGE){ stA((STKT), ((BI) + 3) & 3); stB((STKT), ((BI) + 3) & 3); } \
  __builtin_amdgcn_sched_barrier(0); \
  __builtin_amdgcn_s_setprio(1); \
  _Pragma("unroll") \
  for (int mi = 0; mi < 8; mi++) \
    _Pragma("unroll") \
    for (int nf = 0; nf < 4; nf++) \
      acc[mi][nf] = __builtin_amdgcn_mfma_f32_16x16x32_bf16(afr[mi], bfr[nf], acc[mi][nf], 0, 0, 0); \
  __builtin_amdgcn_s_setprio(0); \
  WAITC; \
  __builtin_amdgcn_s_barrier(); \
}

  // prologue: stage tiles 0,1,2; wait tile 0 landed (8 still outstanding)
  stA(0, 0);  stB(0, 0);
  stA(32, 1); stB(32, 1);
  stA(64, 2); stB(64, 2);
  VMCNT(8);
  __builtin_amdgcn_s_barrier();

  // tiles 0..27: steady state (tile k stages tile k+3, end-wait vmcnt(8))
  for (int kk = 0; kk < 28; kk += 4){
    TILE(0, (kk + 3) << 5, 1, VMCNT(8));
    TILE(1, (kk + 4) << 5, 1, VMCNT(8));
    TILE(2, (kk + 5) << 5, 1, VMCNT(8));
    TILE(3, (kk + 6) << 5, 1, VMCNT(8));
  }
  // tile 28 stages tile 31; then drain
  TILE(0, 992, 1, VMCNT(8));
  TILE(1, 0, 0, VMCNT(4));
  TILE(2, 0, 0, VMCNT(0));
  TILE(3, 0, 0, (void)0);
#undef TILE

  // epilogue: D row = (lane>>4)*4 + i, col = lane&15 (m89-verified layout)
  float bv[4];
#pragma unroll
  for (int nf = 0; nf < 4; nf++) bv[nf] = bias[n0 + wn * 64 + nf * 16 + lrow];
  const bool dosig = SIG && (n0 >= 1024);
#pragma unroll
  for (int mf = 0; mf < 8; mf++){
    int r0 = m0 + wm * 128 + mf * 16 + khi * 4;
#pragma unroll
    for (int nf = 0; nf < 4; nf++){
      int c = n0 + wn * 64 + nf * 16 + lrow;
#pragma unroll
      for (int i2 = 0; i2 < 4; i2++){
        float val = acc[mf][nf][i2] + bv[nf];
        size_t o = (size_t)(r0 + i2) * N + c;
        if (EPI == 0){
          if (SIG && dosig) val = 1.f / (1.f + __expf(-val));
          outb[o] = f2bf(val);
        } else {
          float yrow = yv[r0 + i2] + yv[MROWS + r0 + i2];
          outf[o] = acc[mf][nf][i2] * yrow + bv[nf] + resid[o];
        }
      }
    }
  }
}

// ---------------- depthwise causal conv1d (K=4), sliding-window ----------------
__global__ __launch_bounds__(256) void conv_kernel(const u16* __restrict__ uv,
    const float* __restrict__ wc, const float* __restrict__ bc, u16* __restrict__ uc){
  int idx = blockIdx.x * 256 + threadIdx.x;   // (MROWS/16) segs x 128 d-groups
  int d0 = (idx & 127) * 8;
  int m0 = (idx >> 7) * 16;
  int l0 = m0 & (SEQ - 1);
  float4 wv[8]; float bias[8];
#pragma unroll
  for (int j = 0; j < 8; j++){ wv[j] = *(const float4*)(wc + (d0 + j) * 4); bias[j] = bc[d0 + j]; }
  short8 zero8 = {0,0,0,0,0,0,0,0};
  short8 w0 = zero8, w1 = zero8, w2 = zero8;
  if (l0 > 0){
    w0 = *(const short8*)(uv + (size_t)(m0 - 3) * 2048 + d0);
    w1 = *(const short8*)(uv + (size_t)(m0 - 2) * 2048 + d0);
    w2 = *(const short8*)(uv + (size_t)(m0 - 1) * 2048 + d0);
  }
  const u16* pi = uv + (size_t)m0 * 2048 + d0;
  u16* po = uc + (size_t)m0 * 1024 + d0;
#pragma unroll 4
  for (int t = 0; t < 16; t++){
    short8 cur = *(const short8*)pi;  pi += 2048;
    short8 o;
#pragma unroll
    for (int j = 0; j < 8; j++){
      float a = bias[j] + bf2f((u16)w0[j]) * wv[j].x + bf2f((u16)w1[j]) * wv[j].y
                        + bf2f((u16)w2[j]) * wv[j].z + bf2f((u16)cur[j]) * wv[j].w;
      o[j] = (short)f2bf(a);
    }
    *(short8*)po = o;  po += 1024;
    w0 = w1; w1 = w2; w2 = cur;
  }
}

// ---------------- scan pass A (n-split halves: 512 blocks, 2 n/thread) -------------
// Block = (b, c, half); thread owns n0 = half*512 + tid*2 .. +1.  Grid doubles ->
// 2 blocks/CU (8 waves/CU, was 1 wave/SIMD).  ylocal partials -> yl2[half][m].
__global__ __launch_bounds__(256) void scanA(const u16* __restrict__ dbc, const u16* __restrict__ uc,
                                             u16* __restrict__ G, float* __restrict__ P,
                                             float* __restrict__ S, float* __restrict__ yl2){
  int half = blockIdx.x & 1;
  int c = (blockIdx.x >> 1) & (NCHUNK - 1);
  int b = blockIdx.x >> 7;
  int tid = threadIdx.x, n0 = half * 512 + tid * 2;
  __shared__ float part[CHUNK][257];
  __shared__ float red2[CHUNK][5];
  size_t mbase = (size_t)b * SEQ + c * CHUNK;
  float Pv[2] = {1.f, 1.f}, Sv[2] = {0.f, 0.f};
  const u16* pd = dbc + mbase * 3072 + n0;
  const u16* pu = uc + mbase * 1024 + n0;
  u16* pg = G + mbase * 1024 + n0;
#pragma unroll 4
  for (int t = 0; t < CHUNK; t++){
    u16x2 dr = *(const u16x2*)pd;
    u16x2 bm = *(const u16x2*)(pd + 1024);
    u16x2 cm = *(const u16x2*)(pd + 2048);
    u16x2 uu = *(const u16x2*)pu;
    pd += 3072; pu += 1024;
    float contrib = 0.f;
    u16x2 go;
#pragma unroll
    for (int j = 0; j < 2; j++){
      float dec = 1.f / (1.f + __expf(bf2f(dr[j])));   // exp(-softplus) == sigmoid(-x)
      float cf = bf2f(cm[j]);
      Pv[j] *= dec;
      Sv[j] = Sv[j] * dec + bf2f(uu[j]) * bf2f(bm[j]);
      go[j] = f2bf(Pv[j] * cf);
      contrib += Sv[j] * cf;
    }
    *(u16x2*)pg = go;  pg += 1024;
    part[t][tid] = contrib;
  }
  __syncthreads();
  {
    int t = tid & 63, q = tid >> 6;
    float s = 0.f;
#pragma unroll
    for (int j = 0; j < 64; j++) s += part[t][q * 64 + j];
    red2[t][q] = s;
  }
  __syncthreads();
  if (tid < CHUNK)
    yl2[(size_t)half * MROWS + mbase + tid] =
        red2[tid][0] + red2[tid][1] + red2[tid][2] + red2[tid][3];
  int o = (b * NCHUNK + c) * 1024 + n0;
  f32x2 p2 = {Pv[0], Pv[1]};
  f32x2 s2v = {Sv[0], Sv[1]};
  *(f32x2*)(P + o) = p2;
  *(f32x2*)(S + o) = s2v;
}

// ---------------- pass B: chunk-level scan, widened (4096 threads, 1 n each) -------
__global__ void scanB(const float* __restrict__ P, const float* __restrict__ S,
                      float* __restrict__ Hin){
  int idx = blockIdx.x * 256 + threadIdx.x;  // 4096 threads
  int nn = idx & 1023, b = idx >> 10;
  float H = 0.f;
  for (int c = 0; c < NCHUNK; c++){
    int o = (b * NCHUNK + c) * 1024 + nn;
    Hin[o] = H;
    H = H * P[o] + S[o];
  }
}

// ---------------- pass C' (n-split halves): ysg2[half][m] = Hin.G partial + yl2 ----
__global__ __launch_bounds__(256) void scanC(const u16* __restrict__ G, const float* __restrict__ Hin,
                                             const float* __restrict__ yl2, float* __restrict__ ysg2){
  int half = blockIdx.x & 1;
  int c = (blockIdx.x >> 1) & (NCHUNK - 1);
  int b = blockIdx.x >> 7;
  int tid = threadIdx.x, n0 = half * 512 + tid * 2;
  __shared__ float part[CHUNK][257];
  __shared__ float red2[CHUNK][5];
  size_t mbase = (size_t)b * SEQ + c * CHUNK;
  f32x2 h2 = *(const f32x2*)(Hin + (b * NCHUNK + c) * 1024 + n0);
  const u16* pG = G + mbase * 1024 + n0;
#pragma unroll 4
  for (int t = 0; t < CHUNK; t++){
    u16x2 g = *(const u16x2*)pG;  pG += 1024;
    part[t][tid] = h2.x * bf2f(g.x) + h2.y * bf2f(g.y);
  }
  __syncthreads();
  {
    int t = tid & 63, q = tid >> 6;
    float s = 0.f;
#pragma unroll
    for (int j = 0; j < 64; j++) s += part[t][q * 64 + j];
    red2[t][q] = s;
  }
  __syncthreads();
  if (tid < CHUNK)
    ysg2[(size_t)half * MROWS + mbase + tid] =
        red2[tid][0] + red2[tid][1] + red2[tid][2] + red2[tid][3]
        + yl2[(size_t)half * MROWS + mbase + tid];
}

extern "C" void kernel_launch(void* const* d_in, const int* in_sizes, int n_in,
                              void* d_out, int out_size, void* d_ws, size_t ws_size,
                              hipStream_t stream) {
  const float* x      = (const float*)d_in[0];
  const float* ln_g   = (const float*)d_in[1];
  const float* ln_b   = (const float*)d_in[2];
  const float* w_in   = (const float*)d_in[3];
  const float* b_in   = (const float*)d_in[4];
  const float* w_conv = (const float*)d_in[5];
  const float* b_conv = (const float*)d_in[6];
  const float* w_delta= (const float*)d_in[7];
  const float* b_delta= (const float*)d_in[8];
  const float* w_B    = (const float*)d_in[9];
  const float* b_B    = (const float*)d_in[10];
  const float* w_C    = (const float*)d_in[11];
  const float* b_C    = (const float*)d_in[12];
  const float* w_out  = (const float*)d_in[13];
  const float* b_out  = (const float*)d_in[14];

  char* w = (char*)d_ws;
  u16* w_in_bf  = (u16*)w; w += (size_t)2 * 1024 * 1024 * 2;   // 4 MB
  u16* wcat_bf  = (u16*)w; w += (size_t)3 * 1024 * 1024 * 2;   // 6 MB (delta|B|C rows)
  u16* w_out_bf = (u16*)w; w += (size_t)1024 * 1024 * 2;       // 2 MB
  float* bcat   = (float*)w; w += 16384;                        // 3072 floats, padded
  u16* h_bf     = (u16*)w; w += (size_t)MROWS * 1024 * 2;      // 32 MB (later holds G)
  u16* uv_bf    = (u16*)w; w += (size_t)MROWS * 2048 * 2;      // 64 MB (v-half = sigma(v))
  u16* uc_bf    = (u16*)w; w += (size_t)MROWS * 1024 * 2;      // 32 MB
  u16* dbc_bf   = (u16*)w; w += (size_t)MROWS * 3072 * 2;      // 96 MB
  float* P      = (float*)w; w += (size_t)BATCH * NCHUNK * 1024 * 4;
  float* S      = (float*)w; w += (size_t)BATCH * NCHUNK * 1024 * 4;
  float* Hin    = (float*)w; w += (size_t)BATCH * NCHUNK * 1024 * 4;
  float* yl2    = (float*)w; w += (size_t)2 * MROWS * 4;
  float* ysg2   = (float*)w; w += (size_t)2 * MROWS * 4;
  u16* gbuf     = h_bf;   // h dead after GEMM1; holds G

  // fused weight prep + LN (one launch)
  prep_ln_kernel<<<6147 + MROWS, 256, 0, stream>>>(
      w_in, w_delta, w_B, w_C, w_out, b_delta, b_B, b_C,
      w_in_bf, wcat_bf, w_out_bf, bcat, x, ln_g, ln_b, h_bf);

  // in_proj: uv[16384,2048]; v-half (cols>=1024) stored as sigma(v)
  gemm256<0,1><<<dim3((2048/256) * (MROWS/256)), 512, 0, stream>>>(
      h_bf, w_in_bf, b_in, uv_bf, nullptr, nullptr, nullptr, 2048, 1024);

  conv_kernel<<<(MROWS / 16) * 128 / 256, 256, 0, stream>>>(uv_bf, w_conv, b_conv, uc_bf);

  // delta|B|C fused: dbc[16384,3072]
  gemm256<0,0><<<dim3((3072/256) * (MROWS/256)), 512, 0, stream>>>(
      uc_bf, wcat_bf, bcat, dbc_bf, nullptr, nullptr, nullptr, 3072, 1024);

  scanA<<<BATCH * NCHUNK * 2, 256, 0, stream>>>(dbc_bf, uc_bf, gbuf, P, S, yl2);
  scanB<<<16, 256, 0, stream>>>(P, S, Hin);
  scanC<<<BATCH * NCHUNK * 2, 256, 0, stream>>>(gbuf, Hin, yl2, ysg2);

  // out_proj: A = sigma(v) half of uv (lda=2048); epilogue scales by
  // (ysg2[0][r]+ysg2[1][r]), adds bias + residual -> d_out (fp32)
  gemm256<1,0><<<dim3((1024/256) * (MROWS/256)), 512, 0, stream>>>(
      uv_bf + 1024, w_out_bf, b_out, nullptr, (float*)d_out, x, ysg2, 1024, 2048);
}